// Round 11
// baseline (286.574 us; speedup 1.0000x reference)
//
#include <hip/hip_runtime.h>
#include <math.h>

typedef unsigned short U16;
typedef unsigned int u32;
typedef unsigned long long u64;
typedef __attribute__((ext_vector_type(8))) short short8;
typedef __attribute__((ext_vector_type(4))) float f4;

#define LPTS   256     // L
#define MFMA16(a,b,c) __builtin_amdgcn_mfma_f32_16x16x32_bf16(a, b, c, 0, 0, 0)

__device__ __forceinline__ float bf2f(U16 u) {
  return __uint_as_float(((unsigned int)u) << 16);
}
__device__ __forceinline__ U16 f2bf(float f) {
  unsigned int x = __float_as_uint(f);
  return (U16)((x + 0x7fffu + ((x >> 16) & 1u)) >> 16);
}
// packed RNE f32->bf16 pair (bit-identical to f2bf for normal values)
__device__ __forceinline__ u32 pk_bf16(float lo, float hi) {
  u32 r;
  asm("v_cvt_pk_bf16_f32 %0, %1, %2" : "=v"(r) : "v"(lo), "v"(hi));
  return r;
}
// gelu with A&S 7.1.26 erf (|err| <= 1.5e-7); INLINE (R7 win: ILP across 16 chains)
__device__ __forceinline__ float gelu_f(float v) {
  float z = fabsf(v) * 0.70710678f;
  float t = __builtin_amdgcn_rcpf(fmaf(0.3275911f, z, 1.0f));
  float poly = t * fmaf(t, fmaf(t, fmaf(t, fmaf(t, 1.061405429f, -1.453152027f),
                                        1.421413741f), -0.284496736f), 0.254829592f);
  float e = __expf(-z * z);
  float erf_abs = fmaf(-poly, e, 1.0f);
  float erf_s = copysignf(erf_abs, v);
  return 0.5f * v * (1.0f + erf_s);
}
__device__ __forceinline__ void ins4(u32& k0, u32& k1, u32& k2, u32& k3, u32 key) {
  if (key < k3) {
    if (key < k0)      { k3 = k2; k2 = k1; k1 = k0; k0 = key; }
    else if (key < k1) { k3 = k2; k2 = k1; k1 = key; }
    else if (key < k2) { k3 = k2; k2 = key; }
    else               { k3 = key; }
  }
}
// mode-aware element load: 1=bf16 input, 0=fp32 input.
__device__ __forceinline__ float ldf(const void* s, int i, int mode) {
  return mode ? bf2f(((const U16*)s)[i]) : ((const float*)s)[i];
}
// per-WAVE dtype sniff on W_stem (uniform(-0.125,0.125)); no barrier needed.
__device__ __forceinline__ int wave_sniff(const void* w4) {
  int lane = threadIdx.x & 63;
  float v = bf2f(((const U16*)w4)[2 * lane]);
  u64 m = __ballot(fabsf(v) <= 0.1251f);
  return (__popcll(m) >= 56) ? 1 : 0;
}

struct PackArgs {
  const void* src[6];
  int K[6], N[6], KS[6];
  int base[7];        // in short8 units (element base / 8)
};

// ---------------- kernel 0: pack weights (blocks 0..203, coalesced) + stem (204..459) ----------------
__global__ __launch_bounds__(256) void enf_prep(PackArgs pa,
    const void* c, const void* Wst, const void* bst, const void* Wkp, const void* bkp,
    float* __restrict__ cp_ws, float* __restrict__ kk_ws, U16* __restrict__ P)
{
  __shared__ float c_s[2][64];
  __shared__ float cp_s[2][128];
  const int t = threadIdx.x;
  const int mode = wave_sniff(Wst);
  const int bid = blockIdx.x;
  if (bid < 204) {
    int u = bid * 256 + t;               // short8 index: u = (nt*KS+ks)*64 + lane
    if (u < pa.base[6]) {
      int s = 0;
      while (u >= pa.base[s + 1]) ++s;
      int rel = u - pa.base[s];
      int lane8 = rel & 63, rest = rel >> 6;
      int ks = rest % pa.KS[s], nt = rest / pa.KS[s];
      int kb = ks * 32 + ((lane8 >> 4) * 8);
      int n  = nt * 16 + (lane8 & 15);
      U16 vv[8];
#pragma unroll
      for (int j = 0; j < 8; ++j) {
        int k = kb + j;
        U16 v = 0;
        if (k < pa.K[s]) {
          int off = k * pa.N[s] + n;     // adjacent lanes -> adjacent n: coalesced
          v = mode ? ((const U16*)pa.src[s])[off] : f2bf(((const float*)pa.src[s])[off]);
        }
        vv[j] = v;
      }
      *(short8*)(P + (size_t)u * 8) = *(short8*)vv;
    }
  } else {
    const int half = t >> 7, tl = t & 127;
    const int row = (bid - 204) * 2 + half;        // b*256 + l
    if (tl < 64) c_s[half][tl] = ldf(c, row * 64 + tl, mode);
    __syncthreads();
    float acc = 0.f;
#pragma unroll 8
    for (int i = 0; i < 64; ++i) acc = fmaf(c_s[half][i], ldf(Wst, i * 128 + tl, mode), acc);
    float cpv = acc + ldf(bst, tl, mode);
    cp_s[half][tl] = cpv;
    cp_ws[row * 128 + tl] = cpv;
    __syncthreads();
    acc = 0.f;
#pragma unroll 8
    for (int i = 0; i < 128; ++i) acc = fmaf(cp_s[half][i], ldf(Wkp, i * 128 + tl, mode), acc);
    kk_ws[row * 128 + tl] = acc + ldf(bkp, tl, mode);
  }
}

// ---------------- kernel 1: main — 64 q/block (256 rows), 1024 thr (16 waves), LDS 162304 -> 1 blk/CU ----------------
// R11: next fixed-cost doubling; 4 waves/SIMD unchanged. Wave pairs: w>>1 = col-tile, w&1 = row-half.
// Pool time-sharing: poolS: p_sh -> semb_q -> semb_v -> v_in -> ySt
//                    poolH: hidden_q -> hidden_v -> u -> obuf
__global__ __launch_bounds__(1024, 4) void enf_main(
    const void* __restrict__ w4,
    const void* __restrict__ x, const void* __restrict__ p, const void* __restrict__ g,
    const void* __restrict__ Wq_sin, const void* __restrict__ Wv_sin,
    const U16* __restrict__ PWq1, const void* __restrict__ bq1,
    const U16* __restrict__ PWq2, const void* __restrict__ bq2,
    const U16* __restrict__ PWv1, const void* __restrict__ bv1,
    const U16* __restrict__ PWv2, const void* __restrict__ bv2,
    const U16* __restrict__ PWv, const void* __restrict__ bv,
    const U16* __restrict__ PWo1, const void* __restrict__ bo1,
    const void* __restrict__ Wo2, const void* __restrict__ bo2,
    const float* __restrict__ cp_ws, const float* __restrict__ kk_ws,
    void* __restrict__ outp)
{
  __shared__ __align__(16) U16 poolS[256 * 168];   // 86016 B
  __shared__ __align__(16) U16 poolH[256 * 132];   // 67584 B
  __shared__ float wsin_s[128];                    // 512 B: Wq_sin, reloaded to Wv_sin at P4
  __shared__ float xq[128];                        // 512 B
  __shared__ float selDx[256], selDy[256], selB[256];  // 3072 B
  __shared__ float att_s[256 * 4];                 // 4096 B
  __shared__ U16   selL[256];                      // 512 B   -> total 162304 B
  const int t = threadIdx.x;
  const int w = t >> 6, lane = t & 63;          // 16 waves
  const int quad = lane >> 4, cl = lane & 15;
  const int wt = w >> 1;                        // col-tile index (0..7)
  const int rH = (w & 1) * 128;                 // row-half base (0 or 128)
  const int qbase = blockIdx.x * 64;
  const int b = qbase >> 14;
  const int mode = wave_sniff(w4);
  float* p_sh = (float*)poolS;                  // overlay: 512 floats (selection only)

  // ---- P1: load p (256 pts), x (64 queries), Wq_sin -> LDS (disjoint thread ranges) ----
  if (t < 512) p_sh[t] = ldf(p, b * LPTS * 2 + t, mode);
  else if (t < 640) xq[t - 512] = ldf(x, qbase * 2 + (t - 512), mode);
  else if (t < 768) wsin_s[t - 640] = ldf(Wq_sin, t - 640, mode);
  __syncthreads();

  // ---- P2: distances + per-thread top4 + 16-lane butterfly (16 thr/query, 16 pts each) ----
  {
    const int q = t >> 4;                        // 64 queries, 16 threads each
    const float x0 = xq[q * 2 + 0], x1 = xq[q * 2 + 1];
    const int j = t & 15;
    u32 k0 = ~0u, k1 = ~0u, k2 = ~0u, k3 = ~0u;
#pragma unroll
    for (int s = 0; s < 16; ++s) {
      const int l = j * 16 + s;
      float2 pp = *(const float2*)&p_sh[l * 2];
      float dx = __fsub_rn(x0, pp.x);
      float dy = __fsub_rn(x1, pp.y);
      float d  = __fadd_rn(__fmul_rn(dx, dx), __fmul_rn(dy, dy));
      u32 key = (__float_as_uint(d) & 0xFFFFFF00u) | (u32)l;
      ins4(k0, k1, k2, k3, key);
    }
#pragma unroll
    for (int d = 1; d <= 8; d <<= 1) {           // symmetric merge within 16-lane group
      u32 p0 = __shfl_xor(k0, d, 16);
      u32 p1 = __shfl_xor(k1, d, 16);
      u32 p2 = __shfl_xor(k2, d, 16);
      u32 p3 = __shfl_xor(k3, d, 16);
      ins4(k0, k1, k2, k3, p0); ins4(k0, k1, k2, k3, p1);
      ins4(k0, k1, k2, k3, p2); ins4(k0, k1, k2, k3, p3);
    }
    if (j == 0) {                                // 4 writer lanes per wave
      u32 sel[4] = { k0, k1, k2, k3 };
#pragma unroll
      for (int k = 0; k < 4; ++k) {
        int l = (int)(sel[k] & 255u);
        int r = q * 4 + k;
        selL[r]  = (U16)l;
        float dx = __fsub_rn(x0, p_sh[l * 2 + 0]);
        float dy = __fsub_rn(x1, p_sh[l * 2 + 1]);
        float zx = __fadd_rn(__fmul_rn(dx, dx), __fmul_rn(dy, dy));  // bit-identical to d
        selDx[r] = dx;
        selDy[r] = dy;
        float gf = ldf(g, b * LPTS + l, mode);
        selB[r]  = __fmul_rn(1.0f / __fmul_rn(gf, gf), zx);
      }
    }
  }
  __syncthreads();

  // ---- P3: semb_q -> poolS (1024 thr: 256 rows x 4 lanes, contiguous-i, packed stores) ----
  {
    const int r = t >> 2, ln = t & 3;
    const float dx = selDx[r], dy = selDy[r];
    const float c0 = 3.14159274f * (dx + 1.0f);
    const float c1 = 3.14159274f * (dy + 1.0f);
    U16* rowp = poolS + r * 168;
    if (ln == 0) rowp[0] = f2bf(__sinf(c0));
    if (ln == 1) rowp[1] = f2bf(__sinf(c1));
#pragma unroll 1
    for (int i = ln * 16; i < ln * 16 + 16; i += 2) {
      float e0 = __fadd_rn(__fmul_rn(c0, wsin_s[i]),     __fmul_rn(c1, wsin_s[64 + i]));
      float e1 = __fadd_rn(__fmul_rn(c0, wsin_s[i + 1]), __fmul_rn(c1, wsin_s[64 + i + 1]));
      *(u32*)(rowp + 2 + i)  = pk_bf16(__sinf(e0), __sinf(e1));
      *(u32*)(rowp + 66 + i) = pk_bf16(__sinf(e0 + 1.57079637f), __sinf(e1 + 1.57079637f));
    }
#pragma unroll 1
    for (int k = ln; k < 15; k += 4) *(u32*)(rowp + 130 + 2 * k) = 0;   // zero 130..159
  }
  // hoist P4 first B-frag + Wv_sin reload (global loads legal across barrier)
  float wv_tmp = (t < 128) ? ldf(Wv_sin, t, mode) : 0.f;
  short8 h4b0 = *(const short8*)(PWq1 + ((wt * 5) * 64 + lane) * 8);
  __syncthreads();

  // ---- P4: G1 (16 waves: col-tile wt, rows rH..rH+128; poolS -> poolH, gelu); wsin -> Wv_sin ----
  if (t < 128) wsin_s[t] = wv_tmp;
  {
    f4 acc[8];
#pragma unroll
    for (int i = 0; i < 8; ++i) acc[i] = (f4){0.f, 0.f, 0.f, 0.f};
    const U16* pb0 = PWq1 + ((wt * 5) * 64 + lane) * 8;   // +512 per ks
    short8 b0 = h4b0;
#pragma unroll 1
    for (int ks = 0; ks < 5; ++ks) {
      short8 n0 = *(const short8*)(pb0 + (ks + 1) * 512);  // over-read -> PWq2 (safe)
#pragma unroll
      for (int mt = 0; mt < 8; ++mt) {
        short8 a = *(const short8*)(poolS + ((rH + mt * 16 + cl)) * 168 + quad * 8 + ks * 32);
        acc[mt] = MFMA16(a, b0, acc[mt]);
      }
      b0 = n0;
    }
    int col = wt * 16 + cl;
    float bb = ldf(bq1, col, mode);
#pragma unroll
    for (int mt = 0; mt < 8; ++mt)
#pragma unroll
      for (int reg = 0; reg < 4; ++reg)
        poolH[(rH + mt * 16 + quad * 4 + reg) * 132 + col] = f2bf(gelu_f(acc[mt][reg] + bb));
  }
  // hoist P5q first B-frags (v-waves load a harmless valid address in PWq2)
  {
  }
  short8 h5b0, h5b1;
  {
    int hw = wt & 3;
    h5b0 = *(const short8*)(PWq2 + ((2 * hw + 0) * 4 * 64 + lane) * 8);
    h5b1 = *(const short8*)(PWq2 + ((2 * hw + 1) * 4 * 64 + lane) * 8);
  }
  __syncthreads();

  // ---- P5: q-waves (w<8): G2+logits+softmax | v-waves (w>=8): semb_v -> poolS ----
  if (w < 8) {
    const int wl = wt;                           // head index 0..3 (wt = w>>1 for w<8)
    f4 acc[2][8];
#pragma unroll
    for (int i = 0; i < 8; ++i) { acc[0][i] = (f4){0.f,0.f,0.f,0.f}; acc[1][i] = (f4){0.f,0.f,0.f,0.f}; }
    const U16* pb0 = PWq2 + ((2 * wl + 0) * 4 * 64 + lane) * 8;  // +512 per ks
    const U16* pb1 = PWq2 + ((2 * wl + 1) * 4 * 64 + lane) * 8;
    short8 b0 = h5b0;
    short8 b1 = h5b1;
#pragma unroll 1
    for (int ks = 0; ks < 4; ++ks) {
      short8 n0 = *(const short8*)(pb0 + (ks + 1) * 512);        // over-read -> PWv1 (safe)
      short8 n1 = *(const short8*)(pb1 + (ks + 1) * 512);
#pragma unroll
      for (int mt = 0; mt < 8; ++mt) {
        short8 a = *(const short8*)(poolH + (rH + mt * 16 + cl) * 132 + quad * 8 + ks * 32);
        acc[0][mt] = MFMA16(a, b0, acc[0][mt]);
        acc[1][mt] = MFMA16(a, b1, acc[1][mt]);
      }
      b0 = n0; b1 = n1;
    }
    // fused logits: row r = rH+mt*16+quad*4+reg -> q = rH/4+mt*4+quad, k = reg.
    const float bq2c0 = ldf(bq2, (2 * wl + 0) * 16 + cl, mode);
    const float bq2c1 = ldf(bq2, (2 * wl + 1) * 16 + cl, mode);
    const float* kkb = kk_ws + (size_t)b * LPTS * 128;
#pragma unroll
    for (int mt = 0; mt < 8; ++mt) {
      float part[4];
#pragma unroll
      for (int reg = 0; reg < 4; ++reg) {
        int r = rH + mt * 16 + quad * 4 + reg;
        const float* kr = kkb + selL[r] * 128;
        float q0 = acc[0][mt][reg] + bq2c0;
        float q1 = acc[1][mt][reg] + bq2c1;
        part[reg] = __fmul_rn(q0, kr[(2 * wl + 0) * 16 + cl]);
        part[reg] = fmaf(q1, kr[(2 * wl + 1) * 16 + cl], part[reg]);
      }
#pragma unroll
      for (int d = 1; d <= 8; d <<= 1) {         // butterfly over cl (16 lanes)
        part[0] += __shfl_xor(part[0], d, 16);
        part[1] += __shfl_xor(part[1], d, 16);
        part[2] += __shfl_xor(part[2], d, 16);
        part[3] += __shfl_xor(part[3], d, 16);
      }
      // parallel softmax tail: lane cl&3 owns k = cl&3 (4-lane groups, register select)
      {
        int q = (rH >> 2) + mt * 4 + quad;
        float pr = (cl & 2) ? ((cl & 1) ? part[3] : part[2])
                            : ((cl & 1) ? part[1] : part[0]);
        float lg = pr - selB[q * 4 + (cl & 3)];
        float m = fmaxf(lg, __shfl_xor(lg, 1, 4));
        m = fmaxf(m, __shfl_xor(m, 2, 4));
        float e = __expf(lg - m);
        float s = e + __shfl_xor(e, 1, 4);
        s = s + __shfl_xor(s, 2, 4);
        if (cl < 4) att_s[(q * 4 + cl) * 4 + wl] = e / s;
      }
    }
  } else {
    // semb_v -> poolS (512 thr: 256 rows x 2 lanes, contiguous-i, packed stores)
    const int tt = t - 512;
    const int r = tt >> 1, ln2 = tt & 1;
    const float dx = selDx[r], dy = selDy[r];
    const float c0 = 3.14159274f * (dx + 1.0f);
    const float c1 = 3.14159274f * (dy + 1.0f);
    U16* rowp = poolS + r * 168;
    if (ln2 == 0) rowp[0] = f2bf(__sinf(c0));
    if (ln2 == 1) rowp[1] = f2bf(__sinf(c1));
#pragma unroll 1
    for (int i = ln2 * 32; i < ln2 * 32 + 32; i += 2) {
      float e0 = __fadd_rn(__fmul_rn(c0, wsin_s[i]),     __fmul_rn(c1, wsin_s[64 + i]));
      float e1 = __fadd_rn(__fmul_rn(c0, wsin_s[i + 1]), __fmul_rn(c1, wsin_s[64 + i + 1]));
      *(u32*)(rowp + 2 + i)  = pk_bf16(__sinf(e0), __sinf(e1));
      *(u32*)(rowp + 66 + i) = pk_bf16(__sinf(e0 + 1.57079637f), __sinf(e1 + 1.57079637f));
    }
#pragma unroll 1
    for (int k = ln2; k < 15; k += 2) *(u32*)(rowp + 130 + 2 * k) = 0;  // zero 130..159
  }
  // hoist P6 first B-frag
  short8 h6b0 = *(const short8*)(PWv1 + ((wt * 5) * 64 + lane) * 8);
  __syncthreads();

  // ---- P6: G3 (16 waves: col-tile wt, rows rH; poolS -> poolH, gelu) ----
  {
    f4 acc[8];
#pragma unroll
    for (int i = 0; i < 8; ++i) acc[i] = (f4){0.f, 0.f, 0.f, 0.f};
    const U16* pb0 = PWv1 + ((wt * 5) * 64 + lane) * 8;
    short8 b0 = h6b0;
#pragma unroll 1
    for (int ks = 0; ks < 5; ++ks) {
      short8 n0 = *(const short8*)(pb0 + (ks + 1) * 512);  // over-read -> PWv2 (safe)
#pragma unroll
      for (int mt = 0; mt < 8; ++mt) {
        short8 a = *(const short8*)(poolS + (rH + mt * 16 + cl) * 168 + quad * 8 + ks * 32);
        acc[mt] = MFMA16(a, b0, acc[mt]);
      }
      b0 = n0;
    }
    int col = wt * 16 + cl;
    float bb = ldf(bv1, col, mode);
#pragma unroll
    for (int mt = 0; mt < 8; ++mt)
#pragma unroll
      for (int reg = 0; reg < 4; ++reg)
        poolH[(rH + mt * 16 + quad * 4 + reg) * 132 + col] = f2bf(gelu_f(acc[mt][reg] + bb));
  }
  // hoist P7 first B-frags
  short8 h7g = *(const short8*)(PWv2 + ((wt * 4) * 64 + lane) * 8);
  short8 h7b = *(const short8*)(PWv2 + (((8 + wt) * 4) * 64 + lane) * 8);
  __syncthreads();

  // ---- P7: G4 (16 waves: g-tile wt, b-tile 8+wt, rows rH; poolH -> v_in in poolS) ----
  {
    f4 ag[8], ab[8];
#pragma unroll
    for (int i = 0; i < 8; ++i) { ag[i] = (f4){0.f,0.f,0.f,0.f}; ab[i] = (f4){0.f,0.f,0.f,0.f}; }
    const U16* pg = PWv2 + ((wt * 4) * 64 + lane) * 8;
    const U16* pb = PWv2 + (((8 + wt) * 4) * 64 + lane) * 8;
    short8 bg = h7g;
    short8 bb2 = h7b;
#pragma unroll 1
    for (int ks = 0; ks < 4; ++ks) {
      short8 ng = *(const short8*)(pg + (ks + 1) * 512);
      short8 nb = *(const short8*)(pb + (ks + 1) * 512);   // last over-read -> PWv (safe)
#pragma unroll
      for (int mt = 0; mt < 8; ++mt) {
        short8 a = *(const short8*)(poolH + (rH + mt * 16 + cl) * 132 + quad * 8 + ks * 32);
        ag[mt] = MFMA16(a, bg, ag[mt]);
        ab[mt] = MFMA16(a, bb2, ab[mt]);
      }
      bg = ng; bb2 = nb;
    }
    int col = wt * 16 + cl;
    float bgb = ldf(bv2, col, mode), bbb = ldf(bv2, 128 + col, mode);
#pragma unroll
    for (int mt = 0; mt < 8; ++mt)
#pragma unroll
      for (int reg = 0; reg < 4; ++reg) {
        int row = rH + mt * 16 + quad * 4 + reg;
        float cp = cp_ws[(b * LPTS + selL[row]) * 128 + col];
        float vin = __fadd_rn(__fmul_rn(cp, ag[mt][reg] + bgb), ab[mt][reg] + bbb);
        poolS[row * 132 + col] = f2bf(vin);
      }
  }
  // hoist P9 first B-frags (4x short8); h = w>>2, colHalf = w&1 -> nt0 = h*8+colHalf*4
  const int p9h = w >> 2, p9rH = ((w >> 1) & 1) * 32, p9nt0 = (w >> 2) * 8 + (w & 1) * 4;
  short8 h9cb0 = *(const short8*)(PWv + ((p9nt0 + 0) * 4 * 64 + lane) * 8);
  short8 h9cb1 = *(const short8*)(PWv + ((p9nt0 + 1) * 4 * 64 + lane) * 8);
  short8 h9cb2 = *(const short8*)(PWv + ((p9nt0 + 2) * 4 * 64 + lane) * 8);
  short8 h9cb3 = *(const short8*)(PWv + ((p9nt0 + 3) * 4 * 64 + lane) * 8);
  __syncthreads();

  // ---- P8: u[(h*64+q)] = sum_k att * v_in -> poolH; 8 lanes/(q,h), b32 ops, 2 passes ----
  {
    const int sl = t & 7;
#pragma unroll 1
    for (int pass = 0; pass < 2; ++pass) {
      int gqh = (t >> 3) + pass * 128;           // (q,h) pair, 256 total
      int q = gqh & 63, h = gqh >> 6;
      float a0 = att_s[(q * 4 + 0) * 4 + h];
      float a1 = att_s[(q * 4 + 1) * 4 + h];
      float a2 = att_s[(q * 4 + 2) * 4 + h];
      float a3 = att_s[(q * 4 + 3) * 4 + h];
      const U16* v0p = poolS + (q * 4 + 0) * 132;
      const U16* v1p = poolS + (q * 4 + 1) * 132;
      const U16* v2p = poolS + (q * 4 + 2) * 132;
      const U16* v3p = poolS + (q * 4 + 3) * 132;
      U16* up = poolH + (h * 64 + q) * 132;
#pragma unroll 1
      for (int j = 0; j < 8; ++j) {
        int e0 = j * 16 + sl * 2;                // 2 consecutive elems (b32)
        ushort2 v0 = *(const ushort2*)(v0p + e0);
        ushort2 v1 = *(const ushort2*)(v1p + e0);
        ushort2 v2 = *(const ushort2*)(v2p + e0);
        ushort2 v3 = *(const ushort2*)(v3p + e0);
        float s0 = fmaf(a3, bf2f(v3.x), fmaf(a2, bf2f(v2.x), fmaf(a1, bf2f(v1.x), a0 * bf2f(v0.x))));
        float s1 = fmaf(a3, bf2f(v3.y), fmaf(a2, bf2f(v2.y), fmaf(a1, bf2f(v1.y), a0 * bf2f(v0.y))));
        *(u32*)(up + e0) = pk_bf16(s0, s1);
      }
    }
  }
  __syncthreads();

  // ---- P9: G5 y = u_h @ Wv_h + bv -> ySt (poolS, pitch 520, 64 rows) ----
  // wave w: head p9h = w>>2, row-half p9rH = ((w>>1)&1)*32, col-tiles p9nt0..+3
  U16* ySt = poolS;
  {
    f4 acc5[2][4];
#pragma unroll
    for (int i = 0; i < 4; ++i) { acc5[0][i] = (f4){0.f,0.f,0.f,0.f}; acc5[1][i] = (f4){0.f,0.f,0.f,0.f}; }
    const U16* a5p = poolH + (p9h * 64 + p9rH + cl) * 132 + quad * 8;
    short8 cb[4], nb[4];
    cb[0] = h9cb0; cb[1] = h9cb1; cb[2] = h9cb2; cb[3] = h9cb3;
#pragma unroll 1
    for (int ks = 0; ks < 4; ++ks) {
#pragma unroll
      for (int ntl = 0; ntl < 4; ++ntl)          // last iter over-reads into PWo1 (allocated)
        nb[ntl] = *(const short8*)(PWv + (((p9nt0 + ntl) * 4 + ks + 1) * 64 + lane) * 8);
#pragma unroll
      for (int mt = 0; mt < 2; ++mt) {
        short8 a = *(const short8*)(a5p + mt * 16 * 132 + ks * 32);
#pragma unroll
        for (int ntl = 0; ntl < 4; ++ntl) acc5[mt][ntl] = MFMA16(a, cb[ntl], acc5[mt][ntl]);
      }
#pragma unroll
      for (int ntl = 0; ntl < 4; ++ntl) cb[ntl] = nb[ntl];
    }
#pragma unroll
    for (int ntl = 0; ntl < 4; ++ntl) {
      int col = (p9nt0 + ntl) * 16 + cl;
      float bbv = ldf(bv, col, mode);
#pragma unroll
      for (int mt = 0; mt < 2; ++mt)
#pragma unroll
        for (int reg = 0; reg < 4; ++reg) {
          int q = p9rH + mt * 16 + quad * 4 + reg;
          ySt[q * 520 + col] = f2bf(acc5[mt][ntl][reg] + bbv);
        }
    }
  }
  // hoist P10 first B-frags (tiles w*2, w*2+1)
  short8 hAcb0 = *(const short8*)(PWo1 + (((w * 2 + 0) * 16) * 64 + lane) * 8);
  short8 hAcb1 = *(const short8*)(PWo1 + (((w * 2 + 1) * 16) * 64 + lane) * 8);
  __syncthreads();

  // ---- P10: fused out = gelu(y@Wo1+bo1) @ Wo2 + bo2 (wave w -> col-tiles w*2,w*2+1; 4 M-tiles) ----
  {
    f4 acc[4][2];
#pragma unroll
    for (int i = 0; i < 4; ++i) { acc[i][0] = (f4){0.f,0.f,0.f,0.f}; acc[i][1] = (f4){0.f,0.f,0.f,0.f}; }
    const U16* aP = ySt + cl * 520 + quad * 8;
    const U16* bP = PWo1 + ((w * 2) * 16 * 64 + lane) * 8;     // + (ntl*16+ks)*512
    short8 cb[2], nb[2];
    cb[0] = hAcb0; cb[1] = hAcb1;
#pragma unroll 1
    for (int ks = 0; ks < 16; ++ks) {
#pragma unroll
      for (int ntl = 0; ntl < 2; ++ntl)          // last over-read -> old y_bf ws region (allocated)
        nb[ntl] = *(const short8*)(bP + (ntl * 16 + ks + 1) * 512);
#pragma unroll
      for (int mt = 0; mt < 4; ++mt) {
        short8 a = *(const short8*)(aP + mt * 16 * 520 + ks * 32);
#pragma unroll
        for (int ntl = 0; ntl < 2; ++ntl) acc[mt][ntl] = MFMA16(a, cb[ntl], acc[mt][ntl]);
      }
#pragma unroll
      for (int ntl = 0; ntl < 2; ++ntl) cb[ntl] = nb[ntl];
    }
    float oacc[4][4][3];
#pragma unroll
    for (int mt = 0; mt < 4; ++mt)
#pragma unroll
      for (int reg = 0; reg < 4; ++reg) { oacc[mt][reg][0]=0.f; oacc[mt][reg][1]=0.f; oacc[mt][reg][2]=0.f; }
#pragma unroll
    for (int ntl = 0; ntl < 2; ++ntl) {
      int col = (w * 2 + ntl) * 16 + cl;
      float bb = ldf(bo1, col, mode);
      float w0 = ldf(Wo2, col * 3 + 0, mode);
      float w1 = ldf(Wo2, col * 3 + 1, mode);
      float w2 = ldf(Wo2, col * 3 + 2, mode);
#pragma unroll
      for (int mt = 0; mt < 4; ++mt)
#pragma unroll
        for (int reg = 0; reg < 4; ++reg) {
          float y2 = gelu_f(acc[mt][ntl][reg] + bb);
          oacc[mt][reg][0] = fmaf(y2, w0, oacc[mt][reg][0]);
          oacc[mt][reg][1] = fmaf(y2, w1, oacc[mt][reg][1]);
          oacc[mt][reg][2] = fmaf(y2, w2, oacc[mt][reg][2]);
        }
    }
    float* obuf = (float*)poolH;                 // overlay: [16 waves][64 rows][3] = 12288 B
#pragma unroll
    for (int mt = 0; mt < 4; ++mt)
#pragma unroll
      for (int reg = 0; reg < 4; ++reg)
#pragma unroll
        for (int cix = 0; cix < 3; ++cix) {
          float v = oacc[mt][reg][cix];
          v += __shfl_xor(v, 1);
          v += __shfl_xor(v, 2);
          v += __shfl_xor(v, 4);
          v += __shfl_xor(v, 8);
          if (cl == 0) obuf[(w * 64 + mt * 16 + quad * 4 + reg) * 3 + cix] = v;
        }
  }
  __syncthreads();
  if (t < 192) {
    float* obuf = (float*)poolH;
    int row = t / 3, cix = t - row * 3;
    float s = obuf[row * 3 + cix];
#pragma unroll
    for (int ww = 1; ww < 16; ++ww) s += obuf[(ww * 64 + row) * 3 + cix];
    float ov = s + ldf(bo2, cix, mode);
    int pos = (qbase + row) * 3 + cix;
    if (mode) ((U16*)outp)[pos] = f2bf(ov);
    else      ((float*)outp)[pos] = ov;
  }
}

extern "C" void kernel_launch(void* const* d_in, const int* in_sizes, int n_in,
                              void* d_out, int out_size, void* d_ws, size_t ws_size,
                              hipStream_t stream) {
  (void)in_sizes; (void)n_in; (void)out_size; (void)ws_size;

  float* ws     = (float*)d_ws;
  float* cp_ws  = ws;                     // 2*256*128 fp32
  float* kk_ws  = ws + 65536;             // 2*256*128 fp32
  U16*   Pbase  = (U16*)(ws + 131072);    // 417792 U16 = 208896 floats
  U16*   PWq1   = Pbase + 0;
  U16*   PWq2   = Pbase + 20480;
  U16*   PWv1   = Pbase + 36864;
  U16*   PWv2   = Pbase + 57344;
  U16*   PWv    = Pbase + 90112;
  U16*   PWo1   = Pbase + 155648;

  PackArgs pa;
  const int psrc[6] = {7, 9, 12, 14, 18, 20};
  static const int pK[6]  = {130, 128, 130, 128, 128, 512};
  static const int pN[6]  = {128, 128, 128, 256, 512, 512};
  static const int pKS[6] = {5, 4, 5, 4, 4, 16};
  static const int pB8[7] = {0, 2560, 4608, 7168, 11264, 19456, 52224};  // elem base / 8
  for (int i = 0; i < 6; ++i) {
    pa.src[i] = d_in[psrc[i]];
    pa.K[i] = pK[i]; pa.N[i] = pN[i]; pa.KS[i] = pKS[i]; pa.base[i] = pB8[i];
  }
  pa.base[6] = pB8[6];

  hipLaunchKernelGGL(enf_prep, dim3(460), dim3(256), 0, stream,
                     pa, d_in[2], d_in[4], d_in[5], d_in[16], d_in[17],
                     cp_ws, kk_ws, Pbase);
  hipLaunchKernelGGL(enf_main, dim3(512), dim3(1024), 0, stream,
                     d_in[4],                                   // w4 (sniff)
                     d_in[0], d_in[1], d_in[3],                 // x, p, g
                     d_in[6], d_in[11],                         // Wq_sin, Wv_sin
                     PWq1, d_in[8],  PWq2, d_in[10],
                     PWv1, d_in[13], PWv2, d_in[15],
                     PWv,  d_in[19],
                     PWo1, d_in[21], d_in[22], d_in[23],        // Wo1(packed), bo1, Wo2, bo2
                     cp_ws, kk_ws, (void*)d_out);
}

// Round 12
// 264.627 us; speedup vs baseline: 1.0829x; 1.0829x over previous
//
#include <hip/hip_runtime.h>
#include <math.h>

typedef unsigned short U16;
typedef unsigned int u32;
typedef unsigned long long u64;
typedef __attribute__((ext_vector_type(8))) short short8;
typedef __attribute__((ext_vector_type(4))) float f4;

#define LPTS   256     // L
#define MFMA16(a,b,c) __builtin_amdgcn_mfma_f32_16x16x32_bf16(a, b, c, 0, 0, 0)

__device__ __forceinline__ float bf2f(U16 u) {
  return __uint_as_float(((unsigned int)u) << 16);
}
__device__ __forceinline__ U16 f2bf(float f) {
  unsigned int x = __float_as_uint(f);
  return (U16)((x + 0x7fffu + ((x >> 16) & 1u)) >> 16);
}
// packed RNE f32->bf16 pair (bit-identical to f2bf for normal values)
__device__ __forceinline__ u32 pk_bf16(float lo, float hi) {
  u32 r;
  asm("v_cvt_pk_bf16_f32 %0, %1, %2" : "=v"(r) : "v"(lo), "v"(hi));
  return r;
}
// gelu with A&S 7.1.26 erf (|err| <= 1.5e-7); INLINE (R7 win: ILP across 16 chains)
__device__ __forceinline__ float gelu_f(float v) {
  float z = fabsf(v) * 0.70710678f;
  float t = __builtin_amdgcn_rcpf(fmaf(0.3275911f, z, 1.0f));
  float poly = t * fmaf(t, fmaf(t, fmaf(t, fmaf(t, 1.061405429f, -1.453152027f),
                                        1.421413741f), -0.284496736f), 0.254829592f);
  float e = __expf(-z * z);
  float erf_abs = fmaf(-poly, e, 1.0f);
  float erf_s = copysignf(erf_abs, v);
  return 0.5f * v * (1.0f + erf_s);
}
__device__ __forceinline__ void ins4(u32& k0, u32& k1, u32& k2, u32& k3, u32 key) {
  if (key < k3) {
    if (key < k0)      { k3 = k2; k2 = k1; k1 = k0; k0 = key; }
    else if (key < k1) { k3 = k2; k2 = k1; k1 = key; }
    else if (key < k2) { k3 = k2; k2 = key; }
    else               { k3 = key; }
  }
}
// mode-aware element load: 1=bf16 input, 0=fp32 input.
__device__ __forceinline__ float ldf(const void* s, int i, int mode) {
  return mode ? bf2f(((const U16*)s)[i]) : ((const float*)s)[i];
}
// per-WAVE dtype sniff on W_stem (uniform(-0.125,0.125)); no barrier needed.
__device__ __forceinline__ int wave_sniff(const void* w4) {
  int lane = threadIdx.x & 63;
  float v = bf2f(((const U16*)w4)[2 * lane]);
  u64 m = __ballot(fabsf(v) <= 0.1251f);
  return (__popcll(m) >= 56) ? 1 : 0;
}

struct PackArgs {
  const void* src[6];
  int K[6], N[6], KS[6];
  int base[7];        // in short8 units (element base / 8)
};

// ---------------- kernel 0: pack weights (blocks 0..203, coalesced) + stem (204..459) ----------------
__global__ __launch_bounds__(256) void enf_prep(PackArgs pa,
    const void* c, const void* Wst, const void* bst, const void* Wkp, const void* bkp,
    float* __restrict__ cp_ws, float* __restrict__ kk_ws, U16* __restrict__ P)
{
  __shared__ float c_s[2][64];
  __shared__ float cp_s[2][128];
  const int t = threadIdx.x;
  const int mode = wave_sniff(Wst);
  const int bid = blockIdx.x;
  if (bid < 204) {
    int u = bid * 256 + t;               // short8 index: u = (nt*KS+ks)*64 + lane
    if (u < pa.base[6]) {
      int s = 0;
      while (u >= pa.base[s + 1]) ++s;
      int rel = u - pa.base[s];
      int lane8 = rel & 63, rest = rel >> 6;
      int ks = rest % pa.KS[s], nt = rest / pa.KS[s];
      int kb = ks * 32 + ((lane8 >> 4) * 8);
      int n  = nt * 16 + (lane8 & 15);
      U16 vv[8];
#pragma unroll
      for (int j = 0; j < 8; ++j) {
        int k = kb + j;
        U16 v = 0;
        if (k < pa.K[s]) {
          int off = k * pa.N[s] + n;     // adjacent lanes -> adjacent n: coalesced
          v = mode ? ((const U16*)pa.src[s])[off] : f2bf(((const float*)pa.src[s])[off]);
        }
        vv[j] = v;
      }
      *(short8*)(P + (size_t)u * 8) = *(short8*)vv;
    }
  } else {
    const int half = t >> 7, tl = t & 127;
    const int row = (bid - 204) * 2 + half;        // b*256 + l
    if (tl < 64) c_s[half][tl] = ldf(c, row * 64 + tl, mode);
    __syncthreads();
    float acc = 0.f;
#pragma unroll 8
    for (int i = 0; i < 64; ++i) acc = fmaf(c_s[half][i], ldf(Wst, i * 128 + tl, mode), acc);
    float cpv = acc + ldf(bst, tl, mode);
    cp_s[half][tl] = cpv;
    cp_ws[row * 128 + tl] = cpv;
    __syncthreads();
    acc = 0.f;
#pragma unroll 8
    for (int i = 0; i < 128; ++i) acc = fmaf(cp_s[half][i], ldf(Wkp, i * 128 + tl, mode), acc);
    kk_ws[row * 128 + tl] = acc + ldf(bkp, tl, mode);
  }
}

// ---------------- kernel 1: main — 32 q/block (128 rows), 512 thr, LDS 81408 -> 2 blk/CU ----------------
// R12 = R10 revert (verified best). Block-size scan complete: 8q/16q/64q all worse;
// 2 blk/CU co-residency is load-bearing (barrier-drain overlap, R5+R11 evidence).
// Pool time-sharing: poolS: p_sh -> semb_q -> semb_v -> v_in -> ySt
//                    poolH: hidden_q -> hidden_v -> u -> obuf
__global__ __launch_bounds__(512, 4) void enf_main(
    const void* __restrict__ w4,
    const void* __restrict__ x, const void* __restrict__ p, const void* __restrict__ g,
    const void* __restrict__ Wq_sin, const void* __restrict__ Wv_sin,
    const U16* __restrict__ PWq1, const void* __restrict__ bq1,
    const U16* __restrict__ PWq2, const void* __restrict__ bq2,
    const U16* __restrict__ PWv1, const void* __restrict__ bv1,
    const U16* __restrict__ PWv2, const void* __restrict__ bv2,
    const U16* __restrict__ PWv, const void* __restrict__ bv,
    const U16* __restrict__ PWo1, const void* __restrict__ bo1,
    const void* __restrict__ Wo2, const void* __restrict__ bo2,
    const float* __restrict__ cp_ws, const float* __restrict__ kk_ws,
    void* __restrict__ outp)
{
  __shared__ __align__(16) U16 poolS[128 * 168];   // 43008 B
  __shared__ __align__(16) U16 poolH[128 * 132];   // 33792 B
  __shared__ float wsin_s[128];                    // 512 B: Wq_sin, reloaded to Wv_sin at P4
  __shared__ float xq[64];                         // 256 B
  __shared__ float selDx[128], selDy[128], selB[128];  // 1536 B
  __shared__ float att_s[128 * 4];                 // 2048 B
  __shared__ U16   selL[128];                      // 256 B   -> total 81408 B
  const int t = threadIdx.x;
  const int w = t >> 6, lane = t & 63;          // 8 waves
  const int quad = lane >> 4, cl = lane & 15;
  const int qbase = blockIdx.x * 32;
  const int b = qbase >> 14;
  const int mode = wave_sniff(w4);
  float* p_sh = (float*)poolS;                  // overlay: 512 floats (selection only)

  // ---- P1: load x (32 queries), p (256 pts), Wq_sin -> LDS ----
  if (t < 64) xq[t] = ldf(x, qbase * 2 + t, mode);
  if (t < 128) wsin_s[t] = ldf(Wq_sin, t, mode);
  p_sh[t] = ldf(p, b * LPTS * 2 + t, mode);
  __syncthreads();

  // ---- P2: distances + per-thread top4 + 16-lane butterfly (16 thr/query, 16 pts each) ----
  {
    const int q = t >> 4;                        // 32 queries, 16 threads each
    const float x0 = xq[q * 2 + 0], x1 = xq[q * 2 + 1];
    const int j = t & 15;
    u32 k0 = ~0u, k1 = ~0u, k2 = ~0u, k3 = ~0u;
#pragma unroll
    for (int s = 0; s < 16; ++s) {
      const int l = j * 16 + s;
      float2 pp = *(const float2*)&p_sh[l * 2];
      float dx = __fsub_rn(x0, pp.x);
      float dy = __fsub_rn(x1, pp.y);
      float d  = __fadd_rn(__fmul_rn(dx, dx), __fmul_rn(dy, dy));
      u32 key = (__float_as_uint(d) & 0xFFFFFF00u) | (u32)l;
      ins4(k0, k1, k2, k3, key);
    }
#pragma unroll
    for (int d = 1; d <= 8; d <<= 1) {           // symmetric merge within 16-lane group
      u32 p0 = __shfl_xor(k0, d, 16);
      u32 p1 = __shfl_xor(k1, d, 16);
      u32 p2 = __shfl_xor(k2, d, 16);
      u32 p3 = __shfl_xor(k3, d, 16);
      ins4(k0, k1, k2, k3, p0); ins4(k0, k1, k2, k3, p1);
      ins4(k0, k1, k2, k3, p2); ins4(k0, k1, k2, k3, p3);
    }
    if (j == 0) {                                // 4 writer lanes per wave
      u32 sel[4] = { k0, k1, k2, k3 };
#pragma unroll
      for (int k = 0; k < 4; ++k) {
        int l = (int)(sel[k] & 255u);
        int r = q * 4 + k;
        selL[r]  = (U16)l;
        float dx = __fsub_rn(x0, p_sh[l * 2 + 0]);
        float dy = __fsub_rn(x1, p_sh[l * 2 + 1]);
        float zx = __fadd_rn(__fmul_rn(dx, dx), __fmul_rn(dy, dy));  // bit-identical to d
        selDx[r] = dx;
        selDy[r] = dy;
        float gf = ldf(g, b * LPTS + l, mode);
        selB[r]  = __fmul_rn(1.0f / __fmul_rn(gf, gf), zx);
      }
    }
  }
  __syncthreads();

  // ---- P3: semb_q -> poolS (512 thr: 128 rows x 4 lanes, contiguous-i, packed stores) ----
  {
    const int r = t >> 2, ln = t & 3;
    const float dx = selDx[r], dy = selDy[r];
    const float c0 = 3.14159274f * (dx + 1.0f);
    const float c1 = 3.14159274f * (dy + 1.0f);
    U16* rowp = poolS + r * 168;
    if (ln == 0) rowp[0] = f2bf(__sinf(c0));
    if (ln == 1) rowp[1] = f2bf(__sinf(c1));
#pragma unroll 1
    for (int i = ln * 16; i < ln * 16 + 16; i += 2) {
      float e0 = __fadd_rn(__fmul_rn(c0, wsin_s[i]),     __fmul_rn(c1, wsin_s[64 + i]));
      float e1 = __fadd_rn(__fmul_rn(c0, wsin_s[i + 1]), __fmul_rn(c1, wsin_s[64 + i + 1]));
      *(u32*)(rowp + 2 + i)  = pk_bf16(__sinf(e0), __sinf(e1));
      *(u32*)(rowp + 66 + i) = pk_bf16(__sinf(e0 + 1.57079637f), __sinf(e1 + 1.57079637f));
    }
#pragma unroll 1
    for (int k = ln; k < 15; k += 4) *(u32*)(rowp + 130 + 2 * k) = 0;   // zero 130..159
  }
  // hoist P4 first B-frag + Wv_sin reload (global loads legal across barrier)
  float wv_tmp = (t < 128) ? ldf(Wv_sin, t, mode) : 0.f;
  short8 h4b0 = *(const short8*)(PWq1 + ((w * 5) * 64 + lane) * 8);
  __syncthreads();

  // ---- P4: G1 (all 8 waves, poolS -> poolH, gelu); 8 M-tiles, B reused; wsin -> Wv_sin ----
  if (t < 128) wsin_s[t] = wv_tmp;
  {
    f4 acc[8];
#pragma unroll
    for (int i = 0; i < 8; ++i) acc[i] = (f4){0.f, 0.f, 0.f, 0.f};
    const U16* pb0 = PWq1 + ((w * 5) * 64 + lane) * 8;   // +512 per ks
    short8 b0 = h4b0;
#pragma unroll 1
    for (int ks = 0; ks < 5; ++ks) {
      short8 n0 = *(const short8*)(pb0 + (ks + 1) * 512);  // over-read -> PWq2 (safe)
#pragma unroll
      for (int mt = 0; mt < 8; ++mt) {
        short8 a = *(const short8*)(poolS + (mt * 16 + cl) * 168 + quad * 8 + ks * 32);
        acc[mt] = MFMA16(a, b0, acc[mt]);
      }
      b0 = n0;
    }
    int col = w * 16 + cl;
    float bb = ldf(bq1, col, mode);
#pragma unroll
    for (int mt = 0; mt < 8; ++mt)
#pragma unroll
      for (int reg = 0; reg < 4; ++reg)
        poolH[(mt * 16 + quad * 4 + reg) * 132 + col] = f2bf(gelu_f(acc[mt][reg] + bb));
  }
  // hoist P5q first B-frags (w>=4 loads a harmless valid address in PWq2)
  short8 h5b0 = *(const short8*)(PWq2 + ((2 * (w & 3) + 0) * 4 * 64 + lane) * 8);
  short8 h5b1 = *(const short8*)(PWq2 + ((2 * (w & 3) + 1) * 4 * 64 + lane) * 8);
  __syncthreads();

  // ---- P5: q-waves: G2+logits+softmax (poolH -> att_s) | v-waves: semb_v -> poolS ----
  if (w < 4) {
    const int wl = w;                            // wave wl owns cols [32wl,32wl+32) = head wl
    f4 acc[2][8];
#pragma unroll
    for (int i = 0; i < 8; ++i) { acc[0][i] = (f4){0.f,0.f,0.f,0.f}; acc[1][i] = (f4){0.f,0.f,0.f,0.f}; }
    const U16* pb0 = PWq2 + ((2 * wl + 0) * 4 * 64 + lane) * 8;  // +512 per ks
    const U16* pb1 = PWq2 + ((2 * wl + 1) * 4 * 64 + lane) * 8;
    short8 b0 = h5b0;
    short8 b1 = h5b1;
#pragma unroll 1
    for (int ks = 0; ks < 4; ++ks) {
      short8 n0 = *(const short8*)(pb0 + (ks + 1) * 512);        // over-read -> PWv1 (safe)
      short8 n1 = *(const short8*)(pb1 + (ks + 1) * 512);
#pragma unroll
      for (int mt = 0; mt < 8; ++mt) {
        short8 a = *(const short8*)(poolH + (mt * 16 + cl) * 132 + quad * 8 + ks * 32);
        acc[0][mt] = MFMA16(a, b0, acc[0][mt]);
        acc[1][mt] = MFMA16(a, b1, acc[1][mt]);
      }
      b0 = n0; b1 = n1;
    }
    // fused logits: row r = mt*16+quad*4+reg -> q = mt*4+quad, k = reg (thread-local softmax).
    // FULLY unrolled: all acc[][] indices compile-time (scratch-spill guard, R3 lesson).
    const float bq2c0 = ldf(bq2, (2 * wl + 0) * 16 + cl, mode);
    const float bq2c1 = ldf(bq2, (2 * wl + 1) * 16 + cl, mode);
    const float* kkb = kk_ws + (size_t)b * LPTS * 128;
#pragma unroll
    for (int mt = 0; mt < 8; ++mt) {
      float part[4];
#pragma unroll
      for (int reg = 0; reg < 4; ++reg) {
        int r = mt * 16 + quad * 4 + reg;
        const float* kr = kkb + selL[r] * 128;
        float q0 = acc[0][mt][reg] + bq2c0;
        float q1 = acc[1][mt][reg] + bq2c1;
        part[reg] = __fmul_rn(q0, kr[(2 * wl + 0) * 16 + cl]);
        part[reg] = fmaf(q1, kr[(2 * wl + 1) * 16 + cl], part[reg]);
      }
#pragma unroll
      for (int d = 1; d <= 8; d <<= 1) {         // butterfly over cl (16 lanes)
        part[0] += __shfl_xor(part[0], d, 16);
        part[1] += __shfl_xor(part[1], d, 16);
        part[2] += __shfl_xor(part[2], d, 16);
        part[3] += __shfl_xor(part[3], d, 16);
      }
      // parallel softmax tail: lane cl&3 owns k = cl&3 (4-lane groups, register select)
      {
        int q = mt * 4 + quad;
        float pr = (cl & 2) ? ((cl & 1) ? part[3] : part[2])
                            : ((cl & 1) ? part[1] : part[0]);
        float lg = pr - selB[q * 4 + (cl & 3)];
        float m = fmaxf(lg, __shfl_xor(lg, 1, 4));
        m = fmaxf(m, __shfl_xor(m, 2, 4));
        float e = __expf(lg - m);
        float s = e + __shfl_xor(e, 1, 4);
        s = s + __shfl_xor(s, 2, 4);
        if (cl < 4) att_s[(q * 4 + cl) * 4 + wl] = e / s;
      }
    }
  } else {
    // semb_v -> poolS (256 thr: 128 rows x 2 lanes, contiguous-i, packed stores)
    const int tt = t - 256;
    const int r = tt >> 1, ln2 = tt & 1;
    const float dx = selDx[r], dy = selDy[r];
    const float c0 = 3.14159274f * (dx + 1.0f);
    const float c1 = 3.14159274f * (dy + 1.0f);
    U16* rowp = poolS + r * 168;
    if (ln2 == 0) rowp[0] = f2bf(__sinf(c0));
    if (ln2 == 1) rowp[1] = f2bf(__sinf(c1));
#pragma unroll 1
    for (int i = ln2 * 32; i < ln2 * 32 + 32; i += 2) {
      float e0 = __fadd_rn(__fmul_rn(c0, wsin_s[i]),     __fmul_rn(c1, wsin_s[64 + i]));
      float e1 = __fadd_rn(__fmul_rn(c0, wsin_s[i + 1]), __fmul_rn(c1, wsin_s[64 + i + 1]));
      *(u32*)(rowp + 2 + i)  = pk_bf16(__sinf(e0), __sinf(e1));
      *(u32*)(rowp + 66 + i) = pk_bf16(__sinf(e0 + 1.57079637f), __sinf(e1 + 1.57079637f));
    }
#pragma unroll 1
    for (int k = ln2; k < 15; k += 2) *(u32*)(rowp + 130 + 2 * k) = 0;  // zero 130..159
  }
  // hoist P6 first B-frag
  short8 h6b0 = *(const short8*)(PWv1 + ((w * 5) * 64 + lane) * 8);
  __syncthreads();

  // ---- P6: G3 (all 8 waves, poolS -> poolH, gelu); 8 M-tiles ----
  {
    f4 acc[8];
#pragma unroll
    for (int i = 0; i < 8; ++i) acc[i] = (f4){0.f, 0.f, 0.f, 0.f};
    const U16* pb0 = PWv1 + ((w * 5) * 64 + lane) * 8;
    short8 b0 = h6b0;
#pragma unroll 1
    for (int ks = 0; ks < 5; ++ks) {
      short8 n0 = *(const short8*)(pb0 + (ks + 1) * 512);  // over-read -> PWv2 (safe)
#pragma unroll
      for (int mt = 0; mt < 8; ++mt) {
        short8 a = *(const short8*)(poolS + (mt * 16 + cl) * 168 + quad * 8 + ks * 32);
        acc[mt] = MFMA16(a, b0, acc[mt]);
      }
      b0 = n0;
    }
    int col = w * 16 + cl;
    float bb = ldf(bv1, col, mode);
#pragma unroll
    for (int mt = 0; mt < 8; ++mt)
#pragma unroll
      for (int reg = 0; reg < 4; ++reg)
        poolH[(mt * 16 + quad * 4 + reg) * 132 + col] = f2bf(gelu_f(acc[mt][reg] + bb));
  }
  // hoist P7 first B-frags
  short8 h7g = *(const short8*)(PWv2 + ((w * 4) * 64 + lane) * 8);
  short8 h7b = *(const short8*)(PWv2 + (((8 + w) * 4) * 64 + lane) * 8);
  __syncthreads();

  // ---- P7: G4 (all 8 waves: g-tile w, b-tile 8+w; poolH -> v_in in poolS); 8 M-tiles ----
  {
    f4 ag[8], ab[8];
#pragma unroll
    for (int i = 0; i < 8; ++i) { ag[i] = (f4){0.f,0.f,0.f,0.f}; ab[i] = (f4){0.f,0.f,0.f,0.f}; }
    const U16* pg = PWv2 + ((w * 4) * 64 + lane) * 8;
    const U16* pb = PWv2 + (((8 + w) * 4) * 64 + lane) * 8;
    short8 bg = h7g;
    short8 bb2 = h7b;
#pragma unroll 1
    for (int ks = 0; ks < 4; ++ks) {
      short8 ng = *(const short8*)(pg + (ks + 1) * 512);
      short8 nb = *(const short8*)(pb + (ks + 1) * 512);   // last over-read -> PWv (safe)
#pragma unroll
      for (int mt = 0; mt < 8; ++mt) {
        short8 a = *(const short8*)(poolH + (mt * 16 + cl) * 132 + quad * 8 + ks * 32);
        ag[mt] = MFMA16(a, bg, ag[mt]);
        ab[mt] = MFMA16(a, bb2, ab[mt]);
      }
      bg = ng; bb2 = nb;
    }
    int col = w * 16 + cl;
    float bgb = ldf(bv2, col, mode), bbb = ldf(bv2, 128 + col, mode);
#pragma unroll
    for (int mt = 0; mt < 8; ++mt)
#pragma unroll
      for (int reg = 0; reg < 4; ++reg) {
        int row = mt * 16 + quad * 4 + reg;
        float cp = cp_ws[(b * LPTS + selL[row]) * 128 + col];
        float vin = __fadd_rn(__fmul_rn(cp, ag[mt][reg] + bgb), ab[mt][reg] + bbb);
        poolS[row * 132 + col] = f2bf(vin);
      }
  }
  // hoist P9 first B-frags (4x short8)
  short8 h9cb0 = *(const short8*)(PWv + (((w >> 1) * 8 + (w & 1) * 4 + 0) * 4 * 64 + lane) * 8);
  short8 h9cb1 = *(const short8*)(PWv + (((w >> 1) * 8 + (w & 1) * 4 + 1) * 4 * 64 + lane) * 8);
  short8 h9cb2 = *(const short8*)(PWv + (((w >> 1) * 8 + (w & 1) * 4 + 2) * 4 * 64 + lane) * 8);
  short8 h9cb3 = *(const short8*)(PWv + (((w >> 1) * 8 + (w & 1) * 4 + 3) * 4 * 64 + lane) * 8);
  __syncthreads();

  // ---- P8: u[(h*32+q)] = sum_k att * v_in -> poolH; 8 lanes/(q,h), b32 ops, 2 passes ----
  {
    const int sl = t & 7;
#pragma unroll 1
    for (int pass = 0; pass < 2; ++pass) {
      int gqh = (t >> 3) + pass * 64;            // (q,h) pair
      int q = gqh & 31, h = gqh >> 5;
      float a0 = att_s[(q * 4 + 0) * 4 + h];
      float a1 = att_s[(q * 4 + 1) * 4 + h];
      float a2 = att_s[(q * 4 + 2) * 4 + h];
      float a3 = att_s[(q * 4 + 3) * 4 + h];
      const U16* v0p = poolS + (q * 4 + 0) * 132;
      const U16* v1p = poolS + (q * 4 + 1) * 132;
      const U16* v2p = poolS + (q * 4 + 2) * 132;
      const U16* v3p = poolS + (q * 4 + 3) * 132;
      U16* up = poolH + (h * 32 + q) * 132;
#pragma unroll 1
      for (int j = 0; j < 8; ++j) {
        int e0 = j * 16 + sl * 2;                // 2 consecutive elems (b32)
        ushort2 v0 = *(const ushort2*)(v0p + e0);
        ushort2 v1 = *(const ushort2*)(v1p + e0);
        ushort2 v2 = *(const ushort2*)(v2p + e0);
        ushort2 v3 = *(const ushort2*)(v3p + e0);
        float s0 = fmaf(a3, bf2f(v3.x), fmaf(a2, bf2f(v2.x), fmaf(a1, bf2f(v1.x), a0 * bf2f(v0.x))));
        float s1 = fmaf(a3, bf2f(v3.y), fmaf(a2, bf2f(v2.y), fmaf(a1, bf2f(v1.y), a0 * bf2f(v0.y))));
        *(u32*)(up + e0) = pk_bf16(s0, s1);
      }
    }
  }
  __syncthreads();

  // ---- P9: G5 y = u_h @ Wv_h + bv -> ySt (poolS, pitch 520, 32 rows) ----
  U16* ySt = poolS;
  {
    f4 acc5[2][4];
#pragma unroll
    for (int i = 0; i < 4; ++i) { acc5[0][i] = (f4){0.f,0.f,0.f,0.f}; acc5[1][i] = (f4){0.f,0.f,0.f,0.f}; }
    const int h = w >> 1;
    const int nt0 = h * 8 + (w & 1) * 4;
    const U16* a5p = poolH + (h * 32 + cl) * 132 + quad * 8;
    short8 cb[4], nb[4];
    cb[0] = h9cb0; cb[1] = h9cb1; cb[2] = h9cb2; cb[3] = h9cb3;
#pragma unroll 1
    for (int ks = 0; ks < 4; ++ks) {
#pragma unroll
      for (int ntl = 0; ntl < 4; ++ntl)          // last iter over-reads into PWo1 (allocated)
        nb[ntl] = *(const short8*)(PWv + (((nt0 + ntl) * 4 + ks + 1) * 64 + lane) * 8);
#pragma unroll
      for (int mt = 0; mt < 2; ++mt) {
        short8 a = *(const short8*)(a5p + mt * 16 * 132 + ks * 32);
#pragma unroll
        for (int ntl = 0; ntl < 4; ++ntl) acc5[mt][ntl] = MFMA16(a, cb[ntl], acc5[mt][ntl]);
      }
#pragma unroll
      for (int ntl = 0; ntl < 4; ++ntl) cb[ntl] = nb[ntl];
    }
#pragma unroll
    for (int ntl = 0; ntl < 4; ++ntl) {
      int col = (nt0 + ntl) * 16 + cl;
      float bbv = ldf(bv, col, mode);
#pragma unroll
      for (int mt = 0; mt < 2; ++mt)
#pragma unroll
        for (int reg = 0; reg < 4; ++reg) {
          int q = mt * 16 + quad * 4 + reg;
          ySt[q * 520 + col] = f2bf(acc5[mt][ntl][reg] + bbv);
        }
    }
  }
  // hoist P10 first B-frags
  short8 hAcb0 = *(const short8*)(PWo1 + (((w * 4 + 0) * 16) * 64 + lane) * 8);
  short8 hAcb1 = *(const short8*)(PWo1 + (((w * 4 + 1) * 16) * 64 + lane) * 8);
  short8 hAcb2 = *(const short8*)(PWo1 + (((w * 4 + 2) * 16) * 64 + lane) * 8);
  short8 hAcb3 = *(const short8*)(PWo1 + (((w * 4 + 3) * 16) * 64 + lane) * 8);
  __syncthreads();

  // ---- P10: fused out = gelu(y@Wo1+bo1) @ Wo2 + bo2 (wave w -> cols [64w,64w+64); 2 M-tiles) ----
  {
    f4 acc[2][4];
#pragma unroll
    for (int i = 0; i < 4; ++i) { acc[0][i] = (f4){0.f,0.f,0.f,0.f}; acc[1][i] = (f4){0.f,0.f,0.f,0.f}; }
    const U16* aP = ySt + cl * 520 + quad * 8;
    const U16* bP = PWo1 + ((w * 4) * 16 * 64 + lane) * 8;     // + (ntl*16+ks)*512
    short8 cb[4], nb[4];
    cb[0] = hAcb0; cb[1] = hAcb1; cb[2] = hAcb2; cb[3] = hAcb3;
#pragma unroll 1
    for (int ks = 0; ks < 16; ++ks) {
#pragma unroll
      for (int ntl = 0; ntl < 4; ++ntl)          // ks=15 over-read -> old y_bf ws region (allocated)
        nb[ntl] = *(const short8*)(bP + (ntl * 16 + ks + 1) * 512);
#pragma unroll
      for (int mt = 0; mt < 2; ++mt) {
        short8 a = *(const short8*)(aP + mt * 16 * 520 + ks * 32);
#pragma unroll
        for (int ntl = 0; ntl < 4; ++ntl) acc[mt][ntl] = MFMA16(a, cb[ntl], acc[mt][ntl]);
      }
#pragma unroll
      for (int ntl = 0; ntl < 4; ++ntl) cb[ntl] = nb[ntl];
    }
    float oacc[2][4][3];
#pragma unroll
    for (int mt = 0; mt < 2; ++mt)
#pragma unroll
      for (int reg = 0; reg < 4; ++reg) { oacc[mt][reg][0]=0.f; oacc[mt][reg][1]=0.f; oacc[mt][reg][2]=0.f; }
#pragma unroll
    for (int ntl = 0; ntl < 4; ++ntl) {
      int col = (w * 4 + ntl) * 16 + cl;
      float bb = ldf(bo1, col, mode);
      float w0 = ldf(Wo2, col * 3 + 0, mode);
      float w1 = ldf(Wo2, col * 3 + 1, mode);
      float w2 = ldf(Wo2, col * 3 + 2, mode);
#pragma unroll
      for (int mt = 0; mt < 2; ++mt)
#pragma unroll
        for (int reg = 0; reg < 4; ++reg) {
          float y2 = gelu_f(acc[mt][ntl][reg] + bb);
          oacc[mt][reg][0] = fmaf(y2, w0, oacc[mt][reg][0]);
          oacc[mt][reg][1] = fmaf(y2, w1, oacc[mt][reg][1]);
          oacc[mt][reg][2] = fmaf(y2, w2, oacc[mt][reg][2]);
        }
    }
    float* obuf = (float*)poolH;                 // overlay: [8 waves][32 rows][3]
#pragma unroll
    for (int mt = 0; mt < 2; ++mt)
#pragma unroll
      for (int reg = 0; reg < 4; ++reg)
#pragma unroll
        for (int cix = 0; cix < 3; ++cix) {
          float v = oacc[mt][reg][cix];
          v += __shfl_xor(v, 1);
          v += __shfl_xor(v, 2);
          v += __shfl_xor(v, 4);
          v += __shfl_xor(v, 8);
          if (cl == 0) obuf[(w * 32 + mt * 16 + quad * 4 + reg) * 3 + cix] = v;
        }
  }
  __syncthreads();
  if (t < 96) {
    float* obuf = (float*)poolH;
    int row = t / 3, cix = t - row * 3;
    float s = obuf[row * 3 + cix];
#pragma unroll
    for (int ww = 1; ww < 8; ++ww) s += obuf[(ww * 32 + row) * 3 + cix];
    float ov = s + ldf(bo2, cix, mode);
    int pos = (qbase + row) * 3 + cix;
    if (mode) ((U16*)outp)[pos] = f2bf(ov);
    else      ((float*)outp)[pos] = ov;
  }
}

extern "C" void kernel_launch(void* const* d_in, const int* in_sizes, int n_in,
                              void* d_out, int out_size, void* d_ws, size_t ws_size,
                              hipStream_t stream) {
  (void)in_sizes; (void)n_in; (void)out_size; (void)ws_size;

  float* ws     = (float*)d_ws;
  float* cp_ws  = ws;                     // 2*256*128 fp32
  float* kk_ws  = ws + 65536;             // 2*256*128 fp32
  U16*   Pbase  = (U16*)(ws + 131072);    // 417792 U16 = 208896 floats
  U16*   PWq1   = Pbase + 0;
  U16*   PWq2   = Pbase + 20480;
  U16*   PWv1   = Pbase + 36864;
  U16*   PWv2   = Pbase + 57344;
  U16*   PWv    = Pbase + 90112;
  U16*   PWo1   = Pbase + 155648;

  PackArgs pa;
  const int psrc[6] = {7, 9, 12, 14, 18, 20};
  static const int pK[6]  = {130, 128, 130, 128, 128, 512};
  static const int pN[6]  = {128, 128, 128, 256, 512, 512};
  static const int pKS[6] = {5, 4, 5, 4, 4, 16};
  static const int pB8[7] = {0, 2560, 4608, 7168, 11264, 19456, 52224};  // elem base / 8
  for (int i = 0; i < 6; ++i) {
    pa.src[i] = d_in[psrc[i]];
    pa.K[i] = pK[i]; pa.N[i] = pN[i]; pa.KS[i] = pKS[i]; pa.base[i] = pB8[i];
  }
  pa.base[6] = pB8[6];

  hipLaunchKernelGGL(enf_prep, dim3(460), dim3(256), 0, stream,
                     pa, d_in[2], d_in[4], d_in[5], d_in[16], d_in[17],
                     cp_ws, kk_ws, Pbase);
  hipLaunchKernelGGL(enf_main, dim3(1024), dim3(512), 0, stream,
                     d_in[4],                                   // w4 (sniff)
                     d_in[0], d_in[1], d_in[3],                 // x, p, g
                     d_in[6], d_in[11],                         // Wq_sin, Wv_sin
                     PWq1, d_in[8],  PWq2, d_in[10],
                     PWv1, d_in[13], PWv2, d_in[15],
                     PWv,  d_in[19],
                     PWo1, d_in[21], d_in[22], d_in[23],        // Wo1(packed), bo1, Wo2, bo2
                     cp_ws, kk_ws, (void*)d_out);
}